// Round 7
// baseline (655.999 us; speedup 1.0000x reference)
//
#include <hip/hip_runtime.h>
#include <hip/hip_bf16.h>
#include <math.h>

// Problem constants
#define NN 116           // nodes
#define NE 1160          // edges
#define CCH 256          // channels after conv
#define FF 653           // feature dim
#define KP 672           // padded feature stride (bf16), mult of 32
#define MM (NN*CCH)      // 29696 GEMM rows (= 232 * 128)
#define NPAD 768         // padded N for weight matrix (6 * 128)
#define NT6 (NPAD/128)   // 6 N-tiles
#define SZH ((size_t)MM*KP)   // elems per bf16 h buffer

typedef unsigned short ushort;
typedef short bf16x8 __attribute__((ext_vector_type(8)));
typedef float f32x4 __attribute__((ext_vector_type(4)));

// ---- bf16 helpers (bit-level) ----------------------------------------------
__device__ __forceinline__ float bfbits_to_f(ushort u) {
    unsigned int w = ((unsigned int)u) << 16;
    return __uint_as_float(w);
}
__device__ __forceinline__ ushort f_to_bfbits(float f) {   // RTNE
    unsigned int u = __float_as_uint(f);
    u += 0x7FFFu + ((u >> 16) & 1u);
    return (ushort)(u >> 16);
}

__device__ __forceinline__ void gl_lds16(const void* g, void* l) {
    __builtin_amdgcn_global_load_lds(
        (const __attribute__((address_space(1))) unsigned int*)g,
        (__attribute__((address_space(3))) unsigned int*)l, 16, 0, 0);
}

// ---------------------------------------------------------------------------
// CSR build: per-dst incoming-edge source lists.
__global__ void build_csr_k(const int* __restrict__ ei, int* __restrict__ off,
                            int* __restrict__ lst) {
    __shared__ int s_cnt[NN];
    __shared__ int s_off[NN + 1];
    int t = threadIdx.x;
    for (int i = t; i < NN; i += blockDim.x) s_cnt[i] = 0;
    __syncthreads();
    for (int e = t; e < NE; e += blockDim.x) atomicAdd(&s_cnt[ei[NE + e]], 1);
    __syncthreads();
    if (t == 0) {
        s_off[0] = 0;
        for (int i = 0; i < NN; ++i) s_off[i + 1] = s_off[i] + s_cnt[i];
    }
    __syncthreads();
    for (int i = t; i < NN; i += blockDim.x) { off[i] = s_off[i]; s_cnt[i] = 0; }
    if (t == 0) off[NN] = s_off[NN];
    __syncthreads();
    for (int e = t; e < NE; e += blockDim.x) {
        int d = ei[NE + e];
        int p = atomicAdd(&s_cnt[d], 1);
        lst[s_off[d] + p] = ei[e];
    }
}

// ---------------------------------------------------------------------------
// Quantize + concat weights: Wc[2][NPAD][KP] bf16; pass0=Wl, pass1=Wr, zero pad.
__global__ void build_wc_k(const float* __restrict__ wl, const float* __restrict__ wr,
                           ushort* __restrict__ wc) {
    int idx = blockIdx.x * 256 + threadIdx.x;
    const int total = 2 * NPAD * KP;
    if (idx >= total) return;
    int k = idx % KP;
    int rem = idx / KP;
    int n = rem % NPAD;
    int p = rem / NPAD;
    float v = 0.f;
    if (n < FF && k < FF) v = (p ? wr : wl)[(size_t)n * FF + k];
    wc[idx] = f_to_bfbits(v);
}

// ---------------------------------------------------------------------------
// Grouped Conv1d -> bf16 h [MM][KP], zero pads.
// blockIdx.z = 16-out-channel chunk (UNIFORM -> weights/bias on scalar pipe;
// see R4 post-mortem: selector must be blockIdx, not tid arithmetic).
__global__ __launch_bounds__(256) void conv1d_k(
    const float* __restrict__ x, const float* __restrict__ w,
    const float* __restrict__ b, ushort* __restrict__ h) {
    const int f  = blockIdx.x * 256 + threadIdx.x;   // 0..767
    if (f >= KP) return;
    const int n  = blockIdx.y;
    const int o0 = blockIdx.z * 16;   // uniform out-channel chunk
    const int g  = o0 >> 6;           // group
    if (f >= FF) {                    // zero-pad band f in [653, 672)
#pragma unroll
        for (int oo = 0; oo < 16; ++oo)
            h[(size_t)(n * CCH + o0 + oo) * KP + f] = 0;
        return;
    }
    const float* xp = x + ((size_t)n * 64 + g * 16) * 657 + f;
    const float* wq = w + o0 * 80;    // uniform
    float acc[16];
#pragma unroll
    for (int oo = 0; oo < 16; ++oo) acc[oo] = b[o0 + oo];
#pragma unroll
    for (int i = 0; i < 16; ++i) {
        float xv[5];
#pragma unroll
        for (int k = 0; k < 5; ++k) xv[k] = xp[i * 657 + k];
#pragma unroll
        for (int oo = 0; oo < 16; ++oo) {
            const float* wp = wq + oo * 80 + i * 5;   // uniform -> s_load
            acc[oo] = fmaf(xv[0], wp[0], acc[oo]);
            acc[oo] = fmaf(xv[1], wp[1], acc[oo]);
            acc[oo] = fmaf(xv[2], wp[2], acc[oo]);
            acc[oo] = fmaf(xv[3], wp[3], acc[oo]);
            acc[oo] = fmaf(xv[4], wp[4], acc[oo]);
        }
    }
#pragma unroll
    for (int oo = 0; oo < 16; ++oo)
        h[(size_t)(n * CCH + o0 + oo) * KP + f] = f_to_bfbits(acc[oo]);
}

// ---------------------------------------------------------------------------
// Segment-max gather in bf16 domain (layers 1,2). agg row = max over in-edges.
__global__ void seg_max_k(const ushort* __restrict__ h, ushort* __restrict__ agg,
                          const int* __restrict__ off, const int* __restrict__ lst) {
    int j = blockIdx.x * 256 + threadIdx.x;   // 0..21503 = c*84 + chunk
    int c = j / 84;
    int chunk = j % 84;
    int n = blockIdx.y;
    int o0 = off[n], o1 = off[n + 1];
    size_t dsti = ((size_t)(n * CCH + c)) * KP + chunk * 8;
    if (o0 == o1) {
        *(uint4*)(agg + dsti) = make_uint4(0, 0, 0, 0);
        return;
    }
    float m[8];
#pragma unroll
    for (int i = 0; i < 8; ++i) m[i] = -3.4e38f;
    for (int e = o0; e < o1; ++e) {
        int s = lst[e];
        const uint4 v = *(const uint4*)(h + ((size_t)(s * CCH + c)) * KP + chunk * 8);
        unsigned int u[4] = {v.x, v.y, v.z, v.w};
#pragma unroll
        for (int q = 0; q < 4; ++q) {
            float lo = __uint_as_float(u[q] << 16);
            float hi = __uint_as_float(u[q] & 0xFFFF0000u);
            m[2*q]   = fmaxf(m[2*q],   lo);
            m[2*q+1] = fmaxf(m[2*q+1], hi);
        }
    }
    unsigned int o[4];
#pragma unroll
    for (int q = 0; q < 4; ++q) {
        unsigned int a = __float_as_uint(m[2*q])   >> 16;
        unsigned int bq = __float_as_uint(m[2*q+1]) & 0xFFFF0000u;
        o[q] = a | bq;
    }
    *(uint4*)(agg + dsti) = make_uint4(o[0], o[1], o[2], o[3]);
}

// ---------------------------------------------------------------------------
// Layer-3 fused seg-max + node-mean partials (pool o GEMM == GEMM o pool).
// grid (84, 4): y handles 29 nodes; partial SUM of per-node maxes in fp32.
__global__ void seg_pool_k(const ushort* __restrict__ h, float* __restrict__ part,
                           const int* __restrict__ off, const int* __restrict__ lst) {
    int j = blockIdx.x * 256 + threadIdx.x;   // c*84 + chunk
    int c = j / 84;
    int chunk = j % 84;
    int nq = blockIdx.y;
    float s[8];
#pragma unroll
    for (int i = 0; i < 8; ++i) s[i] = 0.f;
    for (int n = nq * 29; n < nq * 29 + 29; ++n) {
        int o0 = off[n], o1 = off[n + 1];
        if (o0 == o1) continue;          // empty segment contributes 0
        float m[8];
#pragma unroll
        for (int i = 0; i < 8; ++i) m[i] = -3.4e38f;
        for (int e = o0; e < o1; ++e) {
            int sr = lst[e];
            const uint4 v = *(const uint4*)(h + ((size_t)(sr * CCH + c)) * KP + chunk * 8);
            unsigned int u[4] = {v.x, v.y, v.z, v.w};
#pragma unroll
            for (int q = 0; q < 4; ++q) {
                float lo = __uint_as_float(u[q] << 16);
                float hi = __uint_as_float(u[q] & 0xFFFF0000u);
                m[2*q]   = fmaxf(m[2*q],   lo);
                m[2*q+1] = fmaxf(m[2*q+1], hi);
            }
        }
#pragma unroll
        for (int i = 0; i < 8; ++i) s[i] += m[i];
    }
    float* dst = part + ((size_t)(nq * CCH + c)) * KP + chunk * 8;
#pragma unroll
    for (int i = 0; i < 8; ++i) dst[i] = s[i];
}

// Combine 4 partials -> bf16 aggP[c][k] (mean over 116 nodes).
__global__ void combine_k(const float* __restrict__ part, ushort* __restrict__ aggP) {
    int j = blockIdx.x * 256 + threadIdx.x;   // c*84 + chunk
    int c = j / 84;
    int chunk = j % 84;
    const float inv = 1.0f / NN;
#pragma unroll 1
    for (int i = 0; i < 8; ++i) {
        size_t o = ((size_t)c) * KP + chunk * 8 + i;
        float s = part[o] + part[(size_t)CCH * KP + o]
                + part[(size_t)2 * CCH * KP + o] + part[(size_t)3 * CCH * KP + o];
        aggP[o] = f_to_bfbits(s * inv);
    }
}

// ---------------------------------------------------------------------------
// Mean over nodes -> bf16 h2P[c][k].
__global__ void pool_k(const ushort* __restrict__ h, ushort* __restrict__ poolm) {
    int j = blockIdx.x * 256 + threadIdx.x;   // c*84 + chunk
    if (j >= 256 * 84) return;
    int c = j / 84;
    int chunk = j % 84;
    float s[8];
#pragma unroll
    for (int i = 0; i < 8; ++i) s[i] = 0.f;
    for (int n = 0; n < NN; ++n) {
        const uint4 v = *(const uint4*)(h + ((size_t)(n * CCH + c)) * KP + chunk * 8);
        unsigned int u[4] = {v.x, v.y, v.z, v.w};
#pragma unroll
        for (int q = 0; q < 4; ++q) {
            s[2*q]   += __uint_as_float(u[q] << 16);
            s[2*q+1] += __uint_as_float(u[q] & 0xFFFF0000u);
        }
    }
    const float inv = 1.0f / NN;
    ushort* dst = poolm + (size_t)c * KP + chunk * 8;
#pragma unroll
    for (int i = 0; i < 8; ++i) dst[i] = f_to_bfbits(s[i] * inv);
}

// ---------------------------------------------------------------------------
// MFMA GEMM: Hnxt[m][n] = sum_k Agg[m][k]Wl[n][k] + sum_k Hcur[m][k]Wr[n][k] + b[n]
// 1D grid, bijective XCD chunking (m204), N-tile fastest within a chunk so the
// 6 blocks sharing an A-panel are temporally/XCD-local (A from L2).
// Both-sides LDS swizzle (rule 21): linear LDS dest, per-lane GLOBAL chunk
// permuted by chunk^((row>>1)&3); ds_read applies the same involution.
__global__ __launch_bounds__(256) void sage_gemm_k(
    const ushort* __restrict__ Agg, const ushort* __restrict__ Hcur,
    const ushort* __restrict__ Wc, const float* __restrict__ bias,
    ushort* __restrict__ Hnxt)
{
    __shared__ ushort As[128 * 32];
    __shared__ ushort Bs[128 * 32];
    const int bid = blockIdx.x;
    const int nwg = gridDim.x;
    const int q   = nwg >> 3, r = nwg & 7;
    const int xcd = bid & 7,  jj = bid >> 3;
    const int wgid = (xcd < r ? xcd * (q + 1) : r * (q + 1) + (xcd - r) * q) + jj;
    const int mt = wgid / NT6;
    const int nt = wgid - mt * NT6;
    const int bm = mt * 128;
    const int bn = nt * 128;
    const int tid  = threadIdx.x;
    const int lane = tid & 63;
    const int wid  = tid >> 6;
    const int wm = (wid >> 1) * 64;
    const int wn = (wid & 1) * 64;

    f32x4 acc[4][4];
#pragma unroll
    for (int i = 0; i < 4; ++i)
#pragma unroll
        for (int j = 0; j < 4; ++j) acc[i][j] = 0.f;

    const int srow   = lane >> 2;                    // 0..15
    const int schunk = lane & 3;                     // 0..3
    const int schk   = (schunk ^ ((srow >> 1) & 3)) * 8;  // swizzled global chunk
    ushort* lA = As + wid * 16 * 32;
    ushort* lB = Bs + wid * 16 * 32;
    const int lr  = lane & 15;
    const int cc  = lane >> 4;                       // 0..3
    const int kc  = (cc ^ ((lr >> 1) & 3)) * 8;      // swizzled read slot

    for (int pass = 0; pass < 2; ++pass) {
        const ushort* Ab = pass ? Hcur : Agg;
        const ushort* Wb = Wc + (size_t)pass * NPAD * KP;
        for (int k0 = 0; k0 < KP; k0 += 32) {
            const ushort* ga0 = Ab + (size_t)(bm + wid * 16 + srow) * KP + k0 + schk;
            const ushort* gb0 = Wb + (size_t)(bn + wid * 16 + srow) * KP + k0 + schk;
            gl_lds16(ga0, lA);
            gl_lds16(ga0 + (size_t)64 * KP, lA + 64 * 32);
            gl_lds16(gb0, lB);
            gl_lds16(gb0 + (size_t)64 * KP, lB + 64 * 32);
            __syncthreads();
            bf16x8 af[4], bfr[4];
#pragma unroll
            for (int i = 0; i < 4; ++i)
                af[i] = *(const bf16x8*)&As[(wm + i * 16 + lr) * 32 + kc];
#pragma unroll
            for (int j = 0; j < 4; ++j)
                bfr[j] = *(const bf16x8*)&Bs[(wn + j * 16 + lr) * 32 + kc];
#pragma unroll
            for (int i = 0; i < 4; ++i)
#pragma unroll
                for (int j = 0; j < 4; ++j)
                    acc[i][j] = __builtin_amdgcn_mfma_f32_16x16x32_bf16(
                        af[i], bfr[j], acc[i][j], 0, 0, 0);
            __syncthreads();
        }
    }
    const int lg = lane >> 4;
#pragma unroll
    for (int j = 0; j < 4; ++j) {
        int n = bn + wn + j * 16 + lr;
        if (n >= KP) continue;
        bool valid = n < FF;
        float bv = valid ? bias[n] : 0.f;
#pragma unroll
        for (int i = 0; i < 4; ++i) {
#pragma unroll
            for (int rgi = 0; rgi < 4; ++rgi) {
                int m = bm + wm + i * 16 + lg * 4 + rgi;
                float v = valid ? (acc[i][j][rgi] + bv) : 0.f;
                Hnxt[(size_t)m * KP + n] = f_to_bfbits(v);
            }
        }
    }
}

// ---------------------------------------------------------------------------
__device__ __forceinline__ float gelu_exact(float v) {
    return 0.5f * v * (1.0f + erff(v * 0.70710678118654752f));
}

__global__ void head_k(const ushort* __restrict__ pool,
                       const float* __restrict__ w1, const float* __restrict__ b1,
                       const float* __restrict__ w2, const float* __restrict__ b2,
                       const float* __restrict__ w3, const float* __restrict__ b3,
                       float* __restrict__ out) {
    __shared__ float row[FF];
    __shared__ float h1[128];
    __shared__ float h2[32];
    __shared__ float sc[4];
    const int c = blockIdx.x;
    const int t = threadIdx.x;
    for (int i = t; i < FF; i += 128) row[i] = bfbits_to_f(pool[(size_t)c * KP + i]);
    __syncthreads();
    {
        const float* wp = w1 + (size_t)t * FF;
        float s = b1[t];
        for (int i = 0; i < FF; ++i) s = fmaf(row[i], wp[i], s);
        h1[t] = gelu_exact(s);
    }
    __syncthreads();
    if (t < 32) {
        const float* wp = w2 + (size_t)t * 128;
        float s = b2[t];
#pragma unroll
        for (int i = 0; i < 128; ++i) s = fmaf(h1[i], wp[i], s);
        h2[t] = gelu_exact(s);
    }
    __syncthreads();
    if (t < 4) {
        const float* wp = w3 + (size_t)t * 32;
        float s = b3[t];
#pragma unroll
        for (int i = 0; i < 32; ++i) s = fmaf(h2[i], wp[i], s);
        sc[t] = s;
    }
    __syncthreads();
    if (t < 4) {
        float mx = fmaxf(fmaxf(sc[0], sc[1]), fmaxf(sc[2], sc[3]));
        float e0 = __expf(sc[0] - mx), e1 = __expf(sc[1] - mx);
        float e2 = __expf(sc[2] - mx), e3 = __expf(sc[3] - mx);
        float inv = 1.0f / (e0 + e1 + e2 + e3);
        float ev = (t == 0) ? e0 : (t == 1) ? e1 : (t == 2) ? e2 : e3;
        out[(size_t)c * 4 + t] = ev * inv;
    }
}

// ---------------------------------------------------------------------------
extern "C" void kernel_launch(void* const* d_in, const int* in_sizes, int n_in,
                              void* d_out, int out_size, void* d_ws, size_t ws_size,
                              hipStream_t stream) {
    const float* x      = (const float*)d_in[0];
    const int*   ei     = (const int*)  d_in[1];
    const float* conv_w = (const float*)d_in[2];
    const float* conv_b = (const float*)d_in[3];
    const float* wl     = (const float*)d_in[4];
    const float* wr     = (const float*)d_in[5];
    const float* sb     = (const float*)d_in[6];
    const float* fc1w   = (const float*)d_in[7];
    const float* fc1b   = (const float*)d_in[8];
    const float* fc2w   = (const float*)d_in[9];
    const float* fc2b   = (const float*)d_in[10];
    const float* fc3w   = (const float*)d_in[11];
    const float* fc3b   = (const float*)d_in[12];
    float* out = (float*)d_out;

    ushort* hA   = (ushort*)d_ws;
    ushort* hB   = hA + SZH;
    ushort* agg  = hB + SZH;
    ushort* wc   = agg + SZH;
    ushort* aggP = wc + (size_t)2 * NPAD * KP;      // [256][KP]
    ushort* h2P  = aggP + (size_t)CCH * KP;         // [256][KP]
    ushort* poolt= h2P + (size_t)CCH * KP;          // [256][KP] tiny-GEMM out
    float*  part = (float*)(poolt + (size_t)CCH * KP);  // [4][256][KP]
    int*    off  = (int*)(part + (size_t)4 * CCH * KP);
    int*    lst  = off + 128;

    build_csr_k<<<1, 256, 0, stream>>>(ei, off, lst);
    build_wc_k<<<(2 * NPAD * KP + 255) / 256, 256, 0, stream>>>(wl, wr, wc);
    {
        dim3 cgrid(3, NN, 16);
        conv1d_k<<<cgrid, 256, 0, stream>>>(x, conv_w, conv_b, hA);
    }

    dim3 sg_grid(84, NN);
    // L1: hA -> hB ; L2: hB -> hA
    seg_max_k<<<sg_grid, 256, 0, stream>>>(hA, agg, off, lst);
    sage_gemm_k<<<MM / 128 * NT6, 256, 0, stream>>>(agg, hA, wc, sb, hB);
    seg_max_k<<<sg_grid, 256, 0, stream>>>(hB, agg, off, lst);
    sage_gemm_k<<<MM / 128 * NT6, 256, 0, stream>>>(agg, hB, wc, sb, hA);
    // L3 pooled: aggP = mean_n(seg_max(hA)), h2P = mean_n(hA); tiny GEMM M=256
    seg_pool_k<<<dim3(84, 4), 256, 0, stream>>>(hA, part, off, lst);
    combine_k<<<84, 256, 0, stream>>>(part, aggP);
    pool_k<<<84, 256, 0, stream>>>(hA, h2P);
    sage_gemm_k<<<(CCH / 128) * NT6, 256, 0, stream>>>(aggP, h2P, wc, sb, poolt);
    head_k<<<CCH, 128, 0, stream>>>(poolt, fc1w, fc1b, fc2w, fc2b, fc3w, fc3b, out);
}

// Round 8
// 622.030 us; speedup vs baseline: 1.0546x; 1.0546x over previous
//
#include <hip/hip_runtime.h>
#include <hip/hip_bf16.h>
#include <math.h>

// Problem constants
#define NN 116           // nodes
#define NE 1160          // edges
#define CCH 256          // channels after conv
#define FF 653           // feature dim
#define KP 672           // padded feature stride (bf16), mult of 32
#define MM (NN*CCH)      // 29696 GEMM rows (= 232 * 128)
#define NPAD 768         // padded N for weight matrix (6 * 128)
#define NT6 (NPAD/128)   // 6 N-tiles
#define SZH ((size_t)MM*KP)   // elems per bf16 h buffer

typedef unsigned short ushort;
typedef short bf16x8 __attribute__((ext_vector_type(8)));
typedef float f32x4 __attribute__((ext_vector_type(4)));

// ---- bf16 helpers (bit-level) ----------------------------------------------
__device__ __forceinline__ float bfbits_to_f(ushort u) {
    unsigned int w = ((unsigned int)u) << 16;
    return __uint_as_float(w);
}
__device__ __forceinline__ ushort f_to_bfbits(float f) {   // RTNE
    unsigned int u = __float_as_uint(f);
    u += 0x7FFFu + ((u >> 16) & 1u);
    return (ushort)(u >> 16);
}

__device__ __forceinline__ void gl_lds16(const void* g, void* l) {
    __builtin_amdgcn_global_load_lds(
        (const __attribute__((address_space(1))) unsigned int*)g,
        (__attribute__((address_space(3))) unsigned int*)l, 16, 0, 0);
}

// ---------------------------------------------------------------------------
// CSR build: per-dst incoming-edge source lists.
__global__ void build_csr_k(const int* __restrict__ ei, int* __restrict__ off,
                            int* __restrict__ lst) {
    __shared__ int s_cnt[NN];
    __shared__ int s_off[NN + 1];
    int t = threadIdx.x;
    for (int i = t; i < NN; i += blockDim.x) s_cnt[i] = 0;
    __syncthreads();
    for (int e = t; e < NE; e += blockDim.x) atomicAdd(&s_cnt[ei[NE + e]], 1);
    __syncthreads();
    if (t == 0) {
        s_off[0] = 0;
        for (int i = 0; i < NN; ++i) s_off[i + 1] = s_off[i] + s_cnt[i];
    }
    __syncthreads();
    for (int i = t; i < NN; i += blockDim.x) { off[i] = s_off[i]; s_cnt[i] = 0; }
    if (t == 0) off[NN] = s_off[NN];
    __syncthreads();
    for (int e = t; e < NE; e += blockDim.x) {
        int d = ei[NE + e];
        int p = atomicAdd(&s_cnt[d], 1);
        lst[s_off[d] + p] = ei[e];
    }
}

// ---------------------------------------------------------------------------
// Quantize + concat weights: Wc[2][NPAD][KP] bf16; pass0=Wl, pass1=Wr, zero pad.
__global__ void build_wc_k(const float* __restrict__ wl, const float* __restrict__ wr,
                           ushort* __restrict__ wc) {
    int idx = blockIdx.x * 256 + threadIdx.x;
    const int total = 2 * NPAD * KP;
    if (idx >= total) return;
    int k = idx % KP;
    int rem = idx / KP;
    int n = rem % NPAD;
    int p = rem / NPAD;
    float v = 0.f;
    if (n < FF && k < FF) v = (p ? wr : wl)[(size_t)n * FF + k];
    wc[idx] = f_to_bfbits(v);
}

// ---------------------------------------------------------------------------
// Grouped Conv1d -> bf16 h [MM][KP], zero pads.
// blockIdx.z = 16-out-channel chunk (UNIFORM -> weights/bias on scalar pipe;
// see R4 post-mortem: selector must be blockIdx, not tid arithmetic).
__global__ __launch_bounds__(256) void conv1d_k(
    const float* __restrict__ x, const float* __restrict__ w,
    const float* __restrict__ b, ushort* __restrict__ h) {
    const int f  = blockIdx.x * 256 + threadIdx.x;   // 0..767
    if (f >= KP) return;
    const int n  = blockIdx.y;
    const int o0 = blockIdx.z * 16;   // uniform out-channel chunk
    const int g  = o0 >> 6;           // group
    if (f >= FF) {                    // zero-pad band f in [653, 672)
#pragma unroll
        for (int oo = 0; oo < 16; ++oo)
            h[(size_t)(n * CCH + o0 + oo) * KP + f] = 0;
        return;
    }
    const float* xp = x + ((size_t)n * 64 + g * 16) * 657 + f;
    const float* wq = w + o0 * 80;    // uniform
    float acc[16];
#pragma unroll
    for (int oo = 0; oo < 16; ++oo) acc[oo] = b[o0 + oo];
#pragma unroll
    for (int i = 0; i < 16; ++i) {
        float xv[5];
#pragma unroll
        for (int k = 0; k < 5; ++k) xv[k] = xp[i * 657 + k];
#pragma unroll
        for (int oo = 0; oo < 16; ++oo) {
            const float* wp = wq + oo * 80 + i * 5;   // uniform -> s_load
            acc[oo] = fmaf(xv[0], wp[0], acc[oo]);
            acc[oo] = fmaf(xv[1], wp[1], acc[oo]);
            acc[oo] = fmaf(xv[2], wp[2], acc[oo]);
            acc[oo] = fmaf(xv[3], wp[3], acc[oo]);
            acc[oo] = fmaf(xv[4], wp[4], acc[oo]);
        }
    }
#pragma unroll
    for (int oo = 0; oo < 16; ++oo)
        h[(size_t)(n * CCH + o0 + oo) * KP + f] = f_to_bfbits(acc[oo]);
}

// ---------------------------------------------------------------------------
// Transposed segment-max (layers 1,2). Block = (channel c, 32-feature chunk).
// All 116 node rows for this (c,chunk) = 116 x 64B cache lines staged in LDS
// once; every dst's edge-max then reads LDS, not L2/L3. Traffic per layer:
// 40MB read + 40MB write (was ~400MB gather).
__global__ __launch_bounds__(256) void seg_maxT_k(
    const ushort* __restrict__ h, ushort* __restrict__ agg,
    const int* __restrict__ off, const int* __restrict__ lst) {
    __shared__ uint4 sh[NN * 4];            // [n][sub] : 32 bf16 per node
    const int c  = blockIdx.x;              // 0..255
    const int f0 = blockIdx.y * 32;         // 0..640
    const int t  = threadIdx.x;
    for (int u = t; u < NN * 4; u += 256) {
        int n = u >> 2, sub = u & 3;
        sh[u] = *(const uint4*)(h + ((size_t)(n * CCH + c)) * KP + f0 + sub * 8);
    }
    __syncthreads();
    for (int u = t; u < NN * 4; u += 256) {
        int n = u >> 2, sub = u & 3;
        int o0 = off[n], o1 = off[n + 1];
        uint4 outv;
        if (o0 == o1) {
            outv = make_uint4(0, 0, 0, 0);
        } else {
            float m[8];
#pragma unroll
            for (int i = 0; i < 8; ++i) m[i] = -3.4e38f;
            for (int e = o0; e < o1; ++e) {
                int s = lst[e];
                uint4 v = sh[s * 4 + sub];
                unsigned int uu[4] = {v.x, v.y, v.z, v.w};
#pragma unroll
                for (int q = 0; q < 4; ++q) {
                    float lo = __uint_as_float(uu[q] << 16);
                    float hi = __uint_as_float(uu[q] & 0xFFFF0000u);
                    m[2*q]   = fmaxf(m[2*q],   lo);
                    m[2*q+1] = fmaxf(m[2*q+1], hi);
                }
            }
            unsigned int o[4];
#pragma unroll
            for (int q = 0; q < 4; ++q) {
                unsigned int a  = __float_as_uint(m[2*q])   >> 16;
                unsigned int bq = __float_as_uint(m[2*q+1]) & 0xFFFF0000u;
                o[q] = a | bq;
            }
            outv = make_uint4(o[0], o[1], o[2], o[3]);
        }
        *(uint4*)(agg + ((size_t)(n * CCH + c)) * KP + f0 + sub * 8) = outv;
    }
}

// ---------------------------------------------------------------------------
// Layer-3 fused: aggP[c][f] = mean_n seg_max(h)[n,c,f], h2P[c][f] = mean_n h.
// Same transposed structure; block reduces over n locally -> writes only means.
__global__ __launch_bounds__(256) void seg_pool2_k(
    const ushort* __restrict__ h, ushort* __restrict__ aggP,
    ushort* __restrict__ h2P,
    const int* __restrict__ off, const int* __restrict__ lst) {
    __shared__ uint4 sh[NN * 4];
    __shared__ float pm[NN][32];            // per-node maxes fp32
    const int c  = blockIdx.x;
    const int f0 = blockIdx.y * 32;
    const int t  = threadIdx.x;
    for (int u = t; u < NN * 4; u += 256) {
        int n = u >> 2, sub = u & 3;
        sh[u] = *(const uint4*)(h + ((size_t)(n * CCH + c)) * KP + f0 + sub * 8);
    }
    __syncthreads();
    for (int u = t; u < NN * 4; u += 256) {
        int n = u >> 2, sub = u & 3;
        int o0 = off[n], o1 = off[n + 1];
        float m[8];
        if (o0 == o1) {
#pragma unroll
            for (int i = 0; i < 8; ++i) m[i] = 0.f;
        } else {
#pragma unroll
            for (int i = 0; i < 8; ++i) m[i] = -3.4e38f;
            for (int e = o0; e < o1; ++e) {
                int s = lst[e];
                uint4 v = sh[s * 4 + sub];
                unsigned int uu[4] = {v.x, v.y, v.z, v.w};
#pragma unroll
                for (int q = 0; q < 4; ++q) {
                    float lo = __uint_as_float(uu[q] << 16);
                    float hi = __uint_as_float(uu[q] & 0xFFFF0000u);
                    m[2*q]   = fmaxf(m[2*q],   lo);
                    m[2*q+1] = fmaxf(m[2*q+1], hi);
                }
            }
            // truncate to bf16 values (exact maxes of bf16 inputs)
#pragma unroll
            for (int i = 0; i < 8; ++i)
                m[i] = __uint_as_float(__float_as_uint(m[i]) & 0xFFFF0000u);
        }
#pragma unroll
        for (int i = 0; i < 8; ++i) pm[n][sub * 8 + i] = m[i];
    }
    __syncthreads();
    if (t < 32) {
        const float inv = 1.0f / NN;
        float sa = 0.f, s2 = 0.f;
        for (int n = 0; n < NN; ++n) {
            sa += pm[n][t];
            uint4 v = sh[n * 4 + (t >> 3)];
            unsigned int w = ((const unsigned int*)&v)[(t >> 1) & 3];
            float hv = (t & 1) ? __uint_as_float(w & 0xFFFF0000u)
                               : __uint_as_float(w << 16);
            s2 += hv;
        }
        aggP[(size_t)c * KP + f0 + t] = f_to_bfbits(sa * inv);
        h2P [(size_t)c * KP + f0 + t] = f_to_bfbits(s2 * inv);
    }
}

// ---------------------------------------------------------------------------
// MFMA GEMM: Hnxt[m][n] = sum_k Agg[m][k]Wl[n][k] + sum_k Hcur[m][k]Wr[n][k] + b[n]
// 1D grid, bijective XCD chunking (m204), N-tile fastest within a chunk so the
// 6 blocks sharing an A-panel are temporally/XCD-local (A from L2).
// Both-sides LDS swizzle (rule 21): linear LDS dest, per-lane GLOBAL chunk
// permuted by chunk^((row>>1)&3); ds_read applies the same involution.
__global__ __launch_bounds__(256) void sage_gemm_k(
    const ushort* __restrict__ Agg, const ushort* __restrict__ Hcur,
    const ushort* __restrict__ Wc, const float* __restrict__ bias,
    ushort* __restrict__ Hnxt)
{
    __shared__ ushort As[128 * 32];
    __shared__ ushort Bs[128 * 32];
    const int bid = blockIdx.x;
    const int nwg = gridDim.x;
    const int q   = nwg >> 3, r = nwg & 7;
    const int xcd = bid & 7,  jj = bid >> 3;
    const int wgid = (xcd < r ? xcd * (q + 1) : r * (q + 1) + (xcd - r) * q) + jj;
    const int mt = wgid / NT6;
    const int nt = wgid - mt * NT6;
    const int bm = mt * 128;
    const int bn = nt * 128;
    const int tid  = threadIdx.x;
    const int lane = tid & 63;
    const int wid  = tid >> 6;
    const int wm = (wid >> 1) * 64;
    const int wn = (wid & 1) * 64;

    f32x4 acc[4][4];
#pragma unroll
    for (int i = 0; i < 4; ++i)
#pragma unroll
        for (int j = 0; j < 4; ++j) acc[i][j] = 0.f;

    const int srow   = lane >> 2;                    // 0..15
    const int schunk = lane & 3;                     // 0..3
    const int schk   = (schunk ^ ((srow >> 1) & 3)) * 8;  // swizzled global chunk
    ushort* lA = As + wid * 16 * 32;
    ushort* lB = Bs + wid * 16 * 32;
    const int lr  = lane & 15;
    const int cc  = lane >> 4;                       // 0..3
    const int kc  = (cc ^ ((lr >> 1) & 3)) * 8;      // swizzled read slot

    for (int pass = 0; pass < 2; ++pass) {
        const ushort* Ab = pass ? Hcur : Agg;
        const ushort* Wb = Wc + (size_t)pass * NPAD * KP;
        for (int k0 = 0; k0 < KP; k0 += 32) {
            const ushort* ga0 = Ab + (size_t)(bm + wid * 16 + srow) * KP + k0 + schk;
            const ushort* gb0 = Wb + (size_t)(bn + wid * 16 + srow) * KP + k0 + schk;
            gl_lds16(ga0, lA);
            gl_lds16(ga0 + (size_t)64 * KP, lA + 64 * 32);
            gl_lds16(gb0, lB);
            gl_lds16(gb0 + (size_t)64 * KP, lB + 64 * 32);
            __syncthreads();
            bf16x8 af[4], bfr[4];
#pragma unroll
            for (int i = 0; i < 4; ++i)
                af[i] = *(const bf16x8*)&As[(wm + i * 16 + lr) * 32 + kc];
#pragma unroll
            for (int j = 0; j < 4; ++j)
                bfr[j] = *(const bf16x8*)&Bs[(wn + j * 16 + lr) * 32 + kc];
#pragma unroll
            for (int i = 0; i < 4; ++i)
#pragma unroll
                for (int j = 0; j < 4; ++j)
                    acc[i][j] = __builtin_amdgcn_mfma_f32_16x16x32_bf16(
                        af[i], bfr[j], acc[i][j], 0, 0, 0);
            __syncthreads();
        }
    }
    const int lg = lane >> 4;
#pragma unroll
    for (int j = 0; j < 4; ++j) {
        int n = bn + wn + j * 16 + lr;
        if (n >= KP) continue;
        bool valid = n < FF;
        float bv = valid ? bias[n] : 0.f;
#pragma unroll
        for (int i = 0; i < 4; ++i) {
#pragma unroll
            for (int rgi = 0; rgi < 4; ++rgi) {
                int m = bm + wm + i * 16 + lg * 4 + rgi;
                float v = valid ? (acc[i][j][rgi] + bv) : 0.f;
                Hnxt[(size_t)m * KP + n] = f_to_bfbits(v);
            }
        }
    }
}

// ---------------------------------------------------------------------------
__device__ __forceinline__ float gelu_exact(float v) {
    return 0.5f * v * (1.0f + erff(v * 0.70710678118654752f));
}

__global__ void head_k(const ushort* __restrict__ pool,
                       const float* __restrict__ w1, const float* __restrict__ b1,
                       const float* __restrict__ w2, const float* __restrict__ b2,
                       const float* __restrict__ w3, const float* __restrict__ b3,
                       float* __restrict__ out) {
    __shared__ float row[FF];
    __shared__ float h1[128];
    __shared__ float h2[32];
    __shared__ float sc[4];
    const int c = blockIdx.x;
    const int t = threadIdx.x;
    for (int i = t; i < FF; i += 128) row[i] = bfbits_to_f(pool[(size_t)c * KP + i]);
    __syncthreads();
    {
        const float* wp = w1 + (size_t)t * FF;
        float s = b1[t];
        for (int i = 0; i < FF; ++i) s = fmaf(row[i], wp[i], s);
        h1[t] = gelu_exact(s);
    }
    __syncthreads();
    if (t < 32) {
        const float* wp = w2 + (size_t)t * 128;
        float s = b2[t];
#pragma unroll
        for (int i = 0; i < 128; ++i) s = fmaf(h1[i], wp[i], s);
        h2[t] = gelu_exact(s);
    }
    __syncthreads();
    if (t < 4) {
        const float* wp = w3 + (size_t)t * 32;
        float s = b3[t];
#pragma unroll
        for (int i = 0; i < 32; ++i) s = fmaf(h2[i], wp[i], s);
        sc[t] = s;
    }
    __syncthreads();
    if (t < 4) {
        float mx = fmaxf(fmaxf(sc[0], sc[1]), fmaxf(sc[2], sc[3]));
        float e0 = __expf(sc[0] - mx), e1 = __expf(sc[1] - mx);
        float e2 = __expf(sc[2] - mx), e3 = __expf(sc[3] - mx);
        float inv = 1.0f / (e0 + e1 + e2 + e3);
        float ev = (t == 0) ? e0 : (t == 1) ? e1 : (t == 2) ? e2 : e3;
        out[(size_t)c * 4 + t] = ev * inv;
    }
}

// ---------------------------------------------------------------------------
extern "C" void kernel_launch(void* const* d_in, const int* in_sizes, int n_in,
                              void* d_out, int out_size, void* d_ws, size_t ws_size,
                              hipStream_t stream) {
    const float* x      = (const float*)d_in[0];
    const int*   ei     = (const int*)  d_in[1];
    const float* conv_w = (const float*)d_in[2];
    const float* conv_b = (const float*)d_in[3];
    const float* wl     = (const float*)d_in[4];
    const float* wr     = (const float*)d_in[5];
    const float* sb     = (const float*)d_in[6];
    const float* fc1w   = (const float*)d_in[7];
    const float* fc1b   = (const float*)d_in[8];
    const float* fc2w   = (const float*)d_in[9];
    const float* fc2b   = (const float*)d_in[10];
    const float* fc3w   = (const float*)d_in[11];
    const float* fc3b   = (const float*)d_in[12];
    float* out = (float*)d_out;

    ushort* hA   = (ushort*)d_ws;
    ushort* hB   = hA + SZH;
    ushort* agg  = hB + SZH;
    ushort* wc   = agg + SZH;
    ushort* aggP = wc + (size_t)2 * NPAD * KP;      // [256][KP]
    ushort* h2P  = aggP + (size_t)CCH * KP;         // [256][KP]
    ushort* poolt= h2P + (size_t)CCH * KP;          // [256][KP] tiny-GEMM out
    int*    off  = (int*)(poolt + (size_t)CCH * KP);
    int*    lst  = off + 128;

    build_csr_k<<<1, 256, 0, stream>>>(ei, off, lst);
    build_wc_k<<<(2 * NPAD * KP + 255) / 256, 256, 0, stream>>>(wl, wr, wc);
    {
        dim3 cgrid(3, NN, 16);
        conv1d_k<<<cgrid, 256, 0, stream>>>(x, conv_w, conv_b, hA);
    }

    dim3 tg(CCH, KP / 32);   // (256, 21)
    // L1: hA -> hB ; L2: hB -> hA
    seg_maxT_k<<<tg, 256, 0, stream>>>(hA, agg, off, lst);
    sage_gemm_k<<<MM / 128 * NT6, 256, 0, stream>>>(agg, hA, wc, sb, hB);
    seg_maxT_k<<<tg, 256, 0, stream>>>(hB, agg, off, lst);
    sage_gemm_k<<<MM / 128 * NT6, 256, 0, stream>>>(agg, hB, wc, sb, hA);
    // L3 pooled: aggP = mean_n(seg_max(hA)), h2P = mean_n(hA); tiny GEMM M=256
    seg_pool2_k<<<tg, 256, 0, stream>>>(hA, aggP, h2P, off, lst);
    sage_gemm_k<<<(CCH / 128) * NT6, 256, 0, stream>>>(aggP, h2P, wc, sb, poolt);
    head_k<<<CCH, 128, 0, stream>>>(poolt, fc1w, fc1b, fc2w, fc2b, fc3w, fc3b, out);
}

// Round 9
// 594.122 us; speedup vs baseline: 1.1041x; 1.0470x over previous
//
#include <hip/hip_runtime.h>
#include <hip/hip_bf16.h>
#include <math.h>

// Problem constants
#define NN 116           // nodes
#define NE 1160          // edges
#define CCH 256          // channels after conv
#define FF 653           // feature dim
#define KP 672           // padded feature stride (bf16), mult of 32
#define MM (NN*CCH)      // 29696 GEMM rows (= 232 * 128)
#define NPAD 768         // padded N for weight matrix (6 * 128)
#define NT6 (NPAD/128)   // 6 N-tiles
#define NKS (2*KP/32)    // 42 K-steps across the two concatenated passes
#define SZH ((size_t)MM*KP)   // elems per bf16 h buffer

typedef unsigned short ushort;
typedef short bf16x8 __attribute__((ext_vector_type(8)));
typedef float f32x4 __attribute__((ext_vector_type(4)));

// ---- bf16 helpers (bit-level) ----------------------------------------------
__device__ __forceinline__ float bfbits_to_f(ushort u) {
    unsigned int w = ((unsigned int)u) << 16;
    return __uint_as_float(w);
}
__device__ __forceinline__ ushort f_to_bfbits(float f) {   // RTNE
    unsigned int u = __float_as_uint(f);
    u += 0x7FFFu + ((u >> 16) & 1u);
    return (ushort)(u >> 16);
}

__device__ __forceinline__ void gl_lds16(const void* g, void* l) {
    __builtin_amdgcn_global_load_lds(
        (const __attribute__((address_space(1))) unsigned int*)g,
        (__attribute__((address_space(3))) unsigned int*)l, 16, 0, 0);
}

// ---------------------------------------------------------------------------
// CSR build: per-dst incoming-edge source lists.
__global__ void build_csr_k(const int* __restrict__ ei, int* __restrict__ off,
                            int* __restrict__ lst) {
    __shared__ int s_cnt[NN];
    __shared__ int s_off[NN + 1];
    int t = threadIdx.x;
    for (int i = t; i < NN; i += blockDim.x) s_cnt[i] = 0;
    __syncthreads();
    for (int e = t; e < NE; e += blockDim.x) atomicAdd(&s_cnt[ei[NE + e]], 1);
    __syncthreads();
    if (t == 0) {
        s_off[0] = 0;
        for (int i = 0; i < NN; ++i) s_off[i + 1] = s_off[i] + s_cnt[i];
    }
    __syncthreads();
    for (int i = t; i < NN; i += blockDim.x) { off[i] = s_off[i]; s_cnt[i] = 0; }
    if (t == 0) off[NN] = s_off[NN];
    __syncthreads();
    for (int e = t; e < NE; e += blockDim.x) {
        int d = ei[NE + e];
        int p = atomicAdd(&s_cnt[d], 1);
        lst[s_off[d] + p] = ei[e];
    }
}

// ---------------------------------------------------------------------------
// Quantize + concat weights: Wc[2][NPAD][KP] bf16; pass0=Wl, pass1=Wr, zero pad.
__global__ void build_wc_k(const float* __restrict__ wl, const float* __restrict__ wr,
                           ushort* __restrict__ wc) {
    int idx = blockIdx.x * 256 + threadIdx.x;
    const int total = 2 * NPAD * KP;
    if (idx >= total) return;
    int k = idx % KP;
    int rem = idx / KP;
    int n = rem % NPAD;
    int p = rem / NPAD;
    float v = 0.f;
    if (n < FF && k < FF) v = (p ? wr : wl)[(size_t)n * FF + k];
    wc[idx] = f_to_bfbits(v);
}

// ---------------------------------------------------------------------------
// Grouped Conv1d -> bf16 h [MM][KP], zero pads.
// blockIdx.z = 16-out-channel chunk (UNIFORM -> weights/bias on scalar pipe;
// see R4 post-mortem: selector must be blockIdx, not tid arithmetic).
__global__ __launch_bounds__(256) void conv1d_k(
    const float* __restrict__ x, const float* __restrict__ w,
    const float* __restrict__ b, ushort* __restrict__ h) {
    const int f  = blockIdx.x * 256 + threadIdx.x;   // 0..767
    if (f >= KP) return;
    const int n  = blockIdx.y;
    const int o0 = blockIdx.z * 16;   // uniform out-channel chunk
    const int g  = o0 >> 6;           // group
    if (f >= FF) {                    // zero-pad band f in [653, 672)
#pragma unroll
        for (int oo = 0; oo < 16; ++oo)
            h[(size_t)(n * CCH + o0 + oo) * KP + f] = 0;
        return;
    }
    const float* xp = x + ((size_t)n * 64 + g * 16) * 657 + f;
    const float* wq = w + o0 * 80;    // uniform
    float acc[16];
#pragma unroll
    for (int oo = 0; oo < 16; ++oo) acc[oo] = b[o0 + oo];
#pragma unroll
    for (int i = 0; i < 16; ++i) {
        float xv[5];
#pragma unroll
        for (int k = 0; k < 5; ++k) xv[k] = xp[i * 657 + k];
#pragma unroll
        for (int oo = 0; oo < 16; ++oo) {
            const float* wp = wq + oo * 80 + i * 5;   // uniform -> s_load
            acc[oo] = fmaf(xv[0], wp[0], acc[oo]);
            acc[oo] = fmaf(xv[1], wp[1], acc[oo]);
            acc[oo] = fmaf(xv[2], wp[2], acc[oo]);
            acc[oo] = fmaf(xv[3], wp[3], acc[oo]);
            acc[oo] = fmaf(xv[4], wp[4], acc[oo]);
        }
    }
#pragma unroll
    for (int oo = 0; oo < 16; ++oo)
        h[(size_t)(n * CCH + o0 + oo) * KP + f] = f_to_bfbits(acc[oo]);
}

// ---------------------------------------------------------------------------
// Transposed segment-max (layers 1,2). Block = (channel c, 32-feature chunk).
// All 116 node rows for this (c,chunk) staged in LDS once; edge-max reads LDS.
__global__ __launch_bounds__(256) void seg_maxT_k(
    const ushort* __restrict__ h, ushort* __restrict__ agg,
    const int* __restrict__ off, const int* __restrict__ lst) {
    __shared__ uint4 sh[NN * 4];            // [n][sub] : 32 bf16 per node
    const int c  = blockIdx.x;              // 0..255
    const int f0 = blockIdx.y * 32;         // 0..640
    const int t  = threadIdx.x;
    for (int u = t; u < NN * 4; u += 256) {
        int n = u >> 2, sub = u & 3;
        sh[u] = *(const uint4*)(h + ((size_t)(n * CCH + c)) * KP + f0 + sub * 8);
    }
    __syncthreads();
    for (int u = t; u < NN * 4; u += 256) {
        int n = u >> 2, sub = u & 3;
        int o0 = off[n], o1 = off[n + 1];
        uint4 outv;
        if (o0 == o1) {
            outv = make_uint4(0, 0, 0, 0);
        } else {
            float m[8];
#pragma unroll
            for (int i = 0; i < 8; ++i) m[i] = -3.4e38f;
            for (int e = o0; e < o1; ++e) {
                int s = lst[e];
                uint4 v = sh[s * 4 + sub];
                unsigned int uu[4] = {v.x, v.y, v.z, v.w};
#pragma unroll
                for (int q = 0; q < 4; ++q) {
                    float lo = __uint_as_float(uu[q] << 16);
                    float hi = __uint_as_float(uu[q] & 0xFFFF0000u);
                    m[2*q]   = fmaxf(m[2*q],   lo);
                    m[2*q+1] = fmaxf(m[2*q+1], hi);
                }
            }
            unsigned int o[4];
#pragma unroll
            for (int q = 0; q < 4; ++q) {
                unsigned int a  = __float_as_uint(m[2*q])   >> 16;
                unsigned int bq = __float_as_uint(m[2*q+1]) & 0xFFFF0000u;
                o[q] = a | bq;
            }
            outv = make_uint4(o[0], o[1], o[2], o[3]);
        }
        *(uint4*)(agg + ((size_t)(n * CCH + c)) * KP + f0 + sub * 8) = outv;
    }
}

// ---------------------------------------------------------------------------
// Layer-3 fused: aggP[c][f] = mean_n seg_max(h)[n,c,f], h2P[c][f] = mean_n h.
__global__ __launch_bounds__(256) void seg_pool2_k(
    const ushort* __restrict__ h, ushort* __restrict__ aggP,
    ushort* __restrict__ h2P,
    const int* __restrict__ off, const int* __restrict__ lst) {
    __shared__ uint4 sh[NN * 4];
    __shared__ float pm[NN][32];            // per-node maxes fp32
    const int c  = blockIdx.x;
    const int f0 = blockIdx.y * 32;
    const int t  = threadIdx.x;
    for (int u = t; u < NN * 4; u += 256) {
        int n = u >> 2, sub = u & 3;
        sh[u] = *(const uint4*)(h + ((size_t)(n * CCH + c)) * KP + f0 + sub * 8);
    }
    __syncthreads();
    for (int u = t; u < NN * 4; u += 256) {
        int n = u >> 2, sub = u & 3;
        int o0 = off[n], o1 = off[n + 1];
        float m[8];
        if (o0 == o1) {
#pragma unroll
            for (int i = 0; i < 8; ++i) m[i] = 0.f;
        } else {
#pragma unroll
            for (int i = 0; i < 8; ++i) m[i] = -3.4e38f;
            for (int e = o0; e < o1; ++e) {
                int s = lst[e];
                uint4 v = sh[s * 4 + sub];
                unsigned int uu[4] = {v.x, v.y, v.z, v.w};
#pragma unroll
                for (int q = 0; q < 4; ++q) {
                    float lo = __uint_as_float(uu[q] << 16);
                    float hi = __uint_as_float(uu[q] & 0xFFFF0000u);
                    m[2*q]   = fmaxf(m[2*q],   lo);
                    m[2*q+1] = fmaxf(m[2*q+1], hi);
                }
            }
#pragma unroll
            for (int i = 0; i < 8; ++i)
                m[i] = __uint_as_float(__float_as_uint(m[i]) & 0xFFFF0000u);
        }
#pragma unroll
        for (int i = 0; i < 8; ++i) pm[n][sub * 8 + i] = m[i];
    }
    __syncthreads();
    if (t < 32) {
        const float inv = 1.0f / NN;
        float sa = 0.f, s2 = 0.f;
        for (int n = 0; n < NN; ++n) {
            sa += pm[n][t];
            uint4 v = sh[n * 4 + (t >> 3)];
            unsigned int w = ((const unsigned int*)&v)[(t >> 1) & 3];
            float hv = (t & 1) ? __uint_as_float(w & 0xFFFF0000u)
                               : __uint_as_float(w << 16);
            s2 += hv;
        }
        aggP[(size_t)c * KP + f0 + t] = f_to_bfbits(sa * inv);
        h2P [(size_t)c * KP + f0 + t] = f_to_bfbits(s2 * inv);
    }
}

// ---------------------------------------------------------------------------
// MFMA GEMM, 2-phase prefetch (T3-minimum): double-buffered LDS, stage K-step
// t+1 BEFORE computing t, ONE barrier per K-step. The compiler's pre-barrier
// vmcnt(0) drain then lands after the MFMA burst, so staging latency hides
// under compute. ds_read (lgkm) and gl_lds (vm) use different counters.
// 1D grid, bijective XCD chunking; both-sides LDS swizzle (rule 21).
__global__ __launch_bounds__(256) void sage_gemm_k(
    const ushort* __restrict__ Agg, const ushort* __restrict__ Hcur,
    const ushort* __restrict__ Wc, const float* __restrict__ bias,
    ushort* __restrict__ Hnxt)
{
    __shared__ ushort As[2][128 * 32];
    __shared__ ushort Bs[2][128 * 32];
    const int bid = blockIdx.x;
    const int nwg = gridDim.x;
    const int q   = nwg >> 3, r = nwg & 7;
    const int xcd = bid & 7,  jj = bid >> 3;
    const int wgid = (xcd < r ? xcd * (q + 1) : r * (q + 1) + (xcd - r) * q) + jj;
    const int mt = wgid / NT6;
    const int nt = wgid - mt * NT6;
    const int bm = mt * 128;
    const int bn = nt * 128;
    const int tid  = threadIdx.x;
    const int lane = tid & 63;
    const int wid  = tid >> 6;
    const int wm = (wid >> 1) * 64;
    const int wn = (wid & 1) * 64;

    f32x4 acc[4][4];
#pragma unroll
    for (int i = 0; i < 4; ++i)
#pragma unroll
        for (int j = 0; j < 4; ++j) acc[i][j] = 0.f;

    const int srow   = lane >> 2;                    // 0..15
    const int schunk = lane & 3;                     // 0..3
    const int schk   = (schunk ^ ((srow >> 1) & 3)) * 8;  // swizzled global chunk
    const int lr  = lane & 15;
    const int cc  = lane >> 4;                       // 0..3
    const int kc  = (cc ^ ((lr >> 1) & 3)) * 8;      // swizzled read slot
    const int ldsoff = wid * 16 * 32;                // wave's staging band

    // stage K-step kk (0..NKS-1) into buffer b
#define STAGE(b, kk) do {                                                     \
        int _kk = (kk);                                                       \
        const ushort* _Ab = (_kk < 21) ? Agg : Hcur;                          \
        const ushort* _Wb = Wc + (size_t)(_kk < 21 ? 0 : 1) * NPAD * KP;      \
        int _k0 = (_kk < 21 ? _kk : _kk - 21) * 32;                           \
        const ushort* _ga = _Ab + (size_t)(bm + wid * 16 + srow) * KP + _k0 + schk; \
        const ushort* _gb = _Wb + (size_t)(bn + wid * 16 + srow) * KP + _k0 + schk; \
        gl_lds16(_ga, &As[b][ldsoff]);                                        \
        gl_lds16(_ga + (size_t)64 * KP, &As[b][ldsoff + 64 * 32]);            \
        gl_lds16(_gb, &Bs[b][ldsoff]);                                        \
        gl_lds16(_gb + (size_t)64 * KP, &Bs[b][ldsoff + 64 * 32]);            \
    } while (0)

#define COMPUTE(b) do {                                                       \
        bf16x8 _af[4], _bf[4];                                                \
        _Pragma("unroll")                                                     \
        for (int i = 0; i < 4; ++i)                                           \
            _af[i] = *(const bf16x8*)&As[b][(wm + i * 16 + lr) * 32 + kc];    \
        _Pragma("unroll")                                                     \
        for (int j = 0; j < 4; ++j)                                           \
            _bf[j] = *(const bf16x8*)&Bs[b][(wn + j * 16 + lr) * 32 + kc];    \
        _Pragma("unroll")                                                     \
        for (int i = 0; i < 4; ++i)                                           \
            _Pragma("unroll")                                                 \
            for (int j = 0; j < 4; ++j)                                       \
                acc[i][j] = __builtin_amdgcn_mfma_f32_16x16x32_bf16(          \
                    _af[i], _bf[j], acc[i][j], 0, 0, 0);                      \
    } while (0)

    STAGE(0, 0);
    __syncthreads();                    // buf0 ready (compiler drains vmcnt)
#pragma unroll 1
    for (int kk = 0; kk < NKS; kk += 2) {
        STAGE(1, kk + 1);               // prefetch next while computing cur
        COMPUTE(0);
        __syncthreads();                // buf1 ready; all done reading buf0
        if (kk + 2 < NKS) STAGE(0, kk + 2);
        COMPUTE(1);
        __syncthreads();                // buf0 ready; all done reading buf1
    }
#undef STAGE
#undef COMPUTE

    const int lg = lane >> 4;
#pragma unroll
    for (int j = 0; j < 4; ++j) {
        int n = bn + wn + j * 16 + lr;
        if (n >= KP) continue;
        bool valid = n < FF;
        float bv = valid ? bias[n] : 0.f;
#pragma unroll
        for (int i = 0; i < 4; ++i) {
#pragma unroll
            for (int rgi = 0; rgi < 4; ++rgi) {
                int m = bm + wm + i * 16 + lg * 4 + rgi;
                float v = valid ? (acc[i][j][rgi] + bv) : 0.f;
                Hnxt[(size_t)m * KP + n] = f_to_bfbits(v);
            }
        }
    }
}

// ---------------------------------------------------------------------------
__device__ __forceinline__ float gelu_exact(float v) {
    return 0.5f * v * (1.0f + erff(v * 0.70710678118654752f));
}

__global__ void head_k(const ushort* __restrict__ pool,
                       const float* __restrict__ w1, const float* __restrict__ b1,
                       const float* __restrict__ w2, const float* __restrict__ b2,
                       const float* __restrict__ w3, const float* __restrict__ b3,
                       float* __restrict__ out) {
    __shared__ float row[FF];
    __shared__ float h1[128];
    __shared__ float h2[32];
    __shared__ float sc[4];
    const int c = blockIdx.x;
    const int t = threadIdx.x;
    for (int i = t; i < FF; i += 128) row[i] = bfbits_to_f(pool[(size_t)c * KP + i]);
    __syncthreads();
    {
        const float* wp = w1 + (size_t)t * FF;
        float s = b1[t];
        for (int i = 0; i < FF; ++i) s = fmaf(row[i], wp[i], s);
        h1[t] = gelu_exact(s);
    }
    __syncthreads();
    if (t < 32) {
        const float* wp = w2 + (size_t)t * 128;
        float s = b2[t];
#pragma unroll
        for (int i = 0; i < 128; ++i) s = fmaf(h1[i], wp[i], s);
        h2[t] = gelu_exact(s);
    }
    __syncthreads();
    if (t < 4) {
        const float* wp = w3 + (size_t)t * 32;
        float s = b3[t];
#pragma unroll
        for (int i = 0; i < 32; ++i) s = fmaf(h2[i], wp[i], s);
        sc[t] = s;
    }
    __syncthreads();
    if (t < 4) {
        float mx = fmaxf(fmaxf(sc[0], sc[1]), fmaxf(sc[2], sc[3]));
        float e0 = __expf(sc[0] - mx), e1 = __expf(sc[1] - mx);
        float e2 = __expf(sc[2] - mx), e3 = __expf(sc[3] - mx);
        float inv = 1.0f / (e0 + e1 + e2 + e3);
        float ev = (t == 0) ? e0 : (t == 1) ? e1 : (t == 2) ? e2 : e3;
        out[(size_t)c * 4 + t] = ev * inv;
    }
}

// ---------------------------------------------------------------------------
extern "C" void kernel_launch(void* const* d_in, const int* in_sizes, int n_in,
                              void* d_out, int out_size, void* d_ws, size_t ws_size,
                              hipStream_t stream) {
    const float* x      = (const float*)d_in[0];
    const int*   ei     = (const int*)  d_in[1];
    const float* conv_w = (const float*)d_in[2];
    const float* conv_b = (const float*)d_in[3];
    const float* wl     = (const float*)d_in[4];
    const float* wr     = (const float*)d_in[5];
    const float* sb     = (const float*)d_in[6];
    const float* fc1w   = (const float*)d_in[7];
    const float* fc1b   = (const float*)d_in[8];
    const float* fc2w   = (const float*)d_in[9];
    const float* fc2b   = (const float*)d_in[10];
    const float* fc3w   = (const float*)d_in[11];
    const float* fc3b   = (const float*)d_in[12];
    float* out = (float*)d_out;

    ushort* hA   = (ushort*)d_ws;
    ushort* hB   = hA + SZH;
    ushort* agg  = hB + SZH;
    ushort* wc   = agg + SZH;
    ushort* aggP = wc + (size_t)2 * NPAD * KP;      // [256][KP]
    ushort* h2P  = aggP + (size_t)CCH * KP;         // [256][KP]
    ushort* poolt= h2P + (size_t)CCH * KP;          // [256][KP] tiny-GEMM out
    int*    off  = (int*)(poolt + (size_t)CCH * KP);
    int*    lst  = off + 128;

    build_csr_k<<<1, 256, 0, stream>>>(ei, off, lst);
    build_wc_k<<<(2 * NPAD * KP + 255) / 256, 256, 0, stream>>>(wl, wr, wc);
    {
        dim3 cgrid(3, NN, 16);
        conv1d_k<<<cgrid, 256, 0, stream>>>(x, conv_w, conv_b, hA);
    }

    dim3 tg(CCH, KP / 32);   // (256, 21)
    // L1: hA -> hB ; L2: hB -> hA
    seg_maxT_k<<<tg, 256, 0, stream>>>(hA, agg, off, lst);
    sage_gemm_k<<<MM / 128 * NT6, 256, 0, stream>>>(agg, hA, wc, sb, hB);
    seg_maxT_k<<<tg, 256, 0, stream>>>(hB, agg, off, lst);
    sage_gemm_k<<<MM / 128 * NT6, 256, 0, stream>>>(agg, hB, wc, sb, hA);
    // L3 pooled: aggP = mean_n(seg_max(hA)), h2P = mean_n(hA); tiny GEMM M=256
    seg_pool2_k<<<tg, 256, 0, stream>>>(hA, aggP, h2P, off, lst);
    sage_gemm_k<<<(CCH / 128) * NT6, 256, 0, stream>>>(aggP, h2P, wc, sb, poolt);
    head_k<<<CCH, 128, 0, stream>>>(poolt, fc1w, fc1b, fc2w, fc2b, fc3w, fc3b, out);
}